// Round 1
// baseline (359.808 us; speedup 1.0000x reference)
//
#include <hip/hip_runtime.h>

// Per-pixel dynamic (involution) conv, N=8 C=256 H=W=128, K=7x7, pad=3, G=1.
// out[n,c,h,w] = sum_{i,j} weight[n,0,i,j,h,w] * x[n,c,h-3+i,w-3+j]
//
// Strategy:
//  - weight reused across all 256 channels -> keep 49 weights x 4 pixels in VGPRs
//  - x reused 49x spatially -> stage per-channel patch in LDS, aligned ds_read_b128
//  - block = (n, 8-row full-width strip, 64-channel chunk): 512 blocks x 256 thr
//  - LDS rows stride 512B so global_load_lds wave writes are contiguous (m104)
//  - all image-edge handling folded into one-time weight-tap zeroing
//  - double-buffer + counted s_waitcnt vmcnt(1) + raw s_barrier (never drain to 0)

#define KH 7
#define KW 7
#define PADC 3
#define HD 128
#define WD 128
#define CD 256
#define TH 8
#define CPB 64
#define PATCH_ROWS 14          // TH + KH - 1
#define ROWF 128               // floats per LDS row (512 B -> wave-contiguous staging)
#define GUARD 4
#define BUF_FLOATS (GUARD + PATCH_ROWS*ROWF + GUARD)   // 1800

__device__ __forceinline__ void gload_lds16(const float* g, float* l) {
  __builtin_amdgcn_global_load_lds(
      (const __attribute__((address_space(1))) void*)g,
      (__attribute__((address_space(3))) void*)l,
      16, 0, 0);
}

__global__ __launch_bounds__(256, 2)
void dyconv_kernel(const float* __restrict__ x,
                   const float* __restrict__ wt,
                   float* __restrict__ out) {
  __shared__ __align__(16) float lds[2][BUF_FLOATS];

  const int t  = threadIdx.x;
  const int l  = t & 31;          // w-quad index
  const int r  = t >> 5;          // output row within strip (0..7)
  const int w0 = l << 2;          // first of 4 output columns

  const int bid   = blockIdx.x;
  const int chunk = bid & 3;      // channel chunk (weight-sharing blocks adjacent)
  const int strip = (bid >> 2) & 15;
  const int n     = bid >> 6;

  const int h0 = strip * TH;
  const int h  = h0 + r;
  const int c0 = chunk * CPB;

  // ---- load 49 float4 per-pixel weights; zero out-of-image taps once ----
  float4 wv[KH][KW];
  {
    const float* wb = wt + (size_t)n * (KH*KW) * (HD*WD) + h * WD + w0;
    #pragma unroll
    for (int i = 0; i < KH; ++i) {
      const int hx = h + i - PADC;
      const bool rowok = (hx >= 0) && (hx < HD);
      #pragma unroll
      for (int j = 0; j < KW; ++j) {
        float4 v = *(const float4*)(wb + (size_t)(i*KW + j) * (HD*WD));
        const int xc = w0 + j - PADC;      // x column touched by component p=0
        if (!rowok || (xc + 0 < 0) || (xc + 0 >= WD)) v.x = 0.f;
        if (!rowok || (xc + 1 < 0) || (xc + 1 >= WD)) v.y = 0.f;
        if (!rowok || (xc + 2 < 0) || (xc + 2 >= WD)) v.z = 0.f;
        if (!rowok || (xc + 3 < 0) || (xc + 3 >= WD)) v.w = 0.f;
        wv[i][j] = v;
      }
    }
  }

  // zero the 16B guard regions once (they stay zero across channels)
  if (t < GUARD) {
    lds[0][t] = 0.f;
    lds[0][GUARD + PATCH_ROWS*ROWF + t] = 0.f;
    lds[1][t] = 0.f;
    lds[1][GUARD + PATCH_ROWS*ROWF + t] = 0.f;
  }

  // ---- staging geometry (448 lane-tasks: round A = 256, round B = 192) ----
  const int rrA = r;              // LDS patch rows 0..7
  const int rrB = 8 + r;          // LDS patch rows 8..13 (threads t<192)
  const bool hasB = (t < 192);
  const int hxA = min(HD-1, max(0, h0 - PADC + rrA));   // clamped: garbage rows
  const int hxB = min(HD-1, max(0, h0 - PADC + rrB));   // hit zeroed weights
  const int srcA = hxA * WD + w0;
  const int srcB = hxB * WD + w0;
  const int dstA = GUARD + rrA * ROWF + w0;
  const int dstB = GUARD + rrB * ROWF + w0;

  const float* xn   = x   + ((size_t)(n * CD + c0)) * (HD*WD);
  float*       outp = out + ((size_t)(n * CD + c0)) * (HD*WD) + h * WD + w0;

  // ---- prologue: stage channel c0 into buffer 0 ----
  gload_lds16(xn + srcA, &lds[0][dstA]);
  if (hasB) gload_lds16(xn + srcB, &lds[0][dstB]);
  asm volatile("s_waitcnt vmcnt(0)" ::: "memory");
  __builtin_amdgcn_s_barrier();
  __builtin_amdgcn_sched_barrier(0);

  int b = 0;
  #pragma unroll 1
  for (int cc = 0; cc < CPB; ++cc) {
    // (1) stage next channel into the other buffer (issued FIRST for vmcnt math)
    if (cc + 1 < CPB) {
      const float* xc = xn + (size_t)(cc + 1) * (HD*WD);
      gload_lds16(xc + srcA, &lds[b ^ 1][dstA]);
      if (hasB) gload_lds16(xc + srcB, &lds[b ^ 1][dstB]);
    }
    __builtin_amdgcn_sched_barrier(0);   // keep stage-issue above everything else

    // (2) compute from current buffer: 7 rows x (3 ds_read_b128 + 28 FMA)
    const float* bufb = &lds[b][GUARD];
    float ax = 0.f, ay = 0.f, az = 0.f, aw = 0.f;
    #pragma unroll
    for (int i = 0; i < KH; ++i) {
      const float* rp = bufb + (r + i) * ROWF + (w0 - 4);   // 16B-aligned
      const float4 q0 = *(const float4*)(rp);
      const float4 q1 = *(const float4*)(rp + 4);
      const float4 q2 = *(const float4*)(rp + 8);
      const float xr[12] = {q0.x,q0.y,q0.z,q0.w, q1.x,q1.y,q1.z,q1.w,
                            q2.x,q2.y,q2.z,q2.w};
      #pragma unroll
      for (int j = 0; j < KW; ++j) {
        ax += wv[i][j].x * xr[j + 1];
        ay += wv[i][j].y * xr[j + 2];
        az += wv[i][j].z * xr[j + 3];
        aw += wv[i][j].w * xr[j + 4];
      }
    }

    // (3) store this channel's 4 outputs (coalesced dwordx4)
    float4 acc; acc.x = ax; acc.y = ay; acc.z = az; acc.w = aw;
    *(float4*)(outp + (size_t)cc * (HD*WD)) = acc;

    // (4) counted wait: stages (issued before store) retired; store may fly
    asm volatile("s_waitcnt vmcnt(1)" ::: "memory");
    __builtin_amdgcn_s_barrier();
    __builtin_amdgcn_sched_barrier(0);
    b ^= 1;
  }
}

extern "C" void kernel_launch(void* const* d_in, const int* in_sizes, int n_in,
                              void* d_out, int out_size, void* d_ws, size_t ws_size,
                              hipStream_t stream) {
  const float* x  = (const float*)d_in[0];
  const float* wt = (const float*)d_in[1];
  float* out      = (float*)d_out;
  // grid: 8 n * 16 strips * 4 channel-chunks = 512 blocks, 256 threads
  hipLaunchKernelGGL(dyconv_kernel, dim3(512), dim3(256), 0, stream, x, wt, out);
}

// Round 3
// 292.411 us; speedup vs baseline: 1.2305x; 1.2305x over previous
//
#include <hip/hip_runtime.h>
#include <stdint.h>

// Per-pixel dynamic (involution) conv, N=8 C=256 H=W=128, K=7x7, pad=3, G=1.
// out[n,c,h,w] = sum_{i,j} weight[n,0,i,j,h,w] * x[n,c,h-3+i,w-3+j]
//
// Round-2 changes vs round-1 (which was L2-bound on rematerialized weight loads
// + LDS bank conflicts from scalarized reads):
//  - 196 weight scalars laundered through empty asm -> cannot be rematerialized,
//    must stay register-resident across the 64-channel loop
//  - LDS reads are explicit inline-asm ds_read_b128 with immediate offsets,
//    2-row software pipeline with counted lgkmcnt(3); waits carry the result
//    regs as "+v" so consumers can't hoist above the wait
//  - static double buffering (channel loop unrolled x2, no dynamic lds[b])
//  - counted s_waitcnt vmcnt(1) staging pipeline (stage issued first, store last)

#define KH 7
#define KW 7
#define PADC 3
#define HD 128
#define WD 128
#define CD 256
#define TH 8
#define CPB 64
#define PATCH_ROWS 14          // TH + KH - 1
#define ROWF 128               // floats per LDS row (512 B): wave-contig staging
#define GUARD 4
#define BUF_FLOATS (GUARD + PATCH_ROWS*ROWF + GUARD)   // 1800 floats, exact fit
#define HW (HD*WD)

typedef float f32x4 __attribute__((ext_vector_type(4)));
typedef __attribute__((address_space(3))) float lds_f;

__device__ __forceinline__ void gload_lds16(const float* g, float* l) {
  __builtin_amdgcn_global_load_lds(
      (const __attribute__((address_space(1))) void*)g,
      (__attribute__((address_space(3))) void*)l, 16, 0, 0);
}

// issue 3 ds_read_b128 at immediate byte offsets (no wait)
#define DS_ISSUE3(P, O0, O1, O2, Q0, Q1, Q2)                        \
  asm volatile("ds_read_b128 %0, %3 offset:" #O0 "\n\t"             \
               "ds_read_b128 %1, %3 offset:" #O1 "\n\t"             \
               "ds_read_b128 %2, %3 offset:" #O2                    \
               : "=&v"(Q0), "=&v"(Q1), "=&v"(Q2) : "v"(P))

// counted wait; ties the waited-on regs so their consumers can't hoist above
#define LGKM_WAIT(N, Q0, Q1, Q2)                                    \
  asm volatile("s_waitcnt lgkmcnt(" #N ")" : "+v"(Q0), "+v"(Q1), "+v"(Q2))

__device__ __forceinline__ float xk(const f32x4 a, const f32x4 b,
                                    const f32x4 c, const int k) {
  return k < 4 ? a[k] : (k < 8 ? b[k - 4] : c[k - 8]);
}

__global__ __launch_bounds__(256, 2)
void dyconv_kernel(const float* __restrict__ x,
                   const float* __restrict__ wt,
                   float* __restrict__ out) {
  __shared__ __align__(16) float lds0[BUF_FLOATS];
  __shared__ __align__(16) float lds1[BUF_FLOATS];

  const int t  = threadIdx.x;
  const int l  = t & 31;
  const int r  = t >> 5;
  const int w0 = l << 2;

  const int bid   = blockIdx.x;
  const int chunk = bid & 3;
  const int strip = (bid >> 2) & 15;
  const int n     = bid >> 6;
  const int h0    = strip * TH;
  const int h     = h0 + r;
  const int c0    = chunk * CPB;

  // ---- per-pixel weights: load, zero out-of-image taps, force residency ----
  float wgt[KH][KW][4];
  {
    const float* wb = wt + (size_t)n * (KH*KW) * HW + h * WD + w0;
    #pragma unroll
    for (int i = 0; i < KH; ++i) {
      const int hx = h + i - PADC;
      const bool rowok = (hx >= 0) && (hx < HD);
      #pragma unroll
      for (int j = 0; j < KW; ++j) {
        float4 v = *(const float4*)(wb + (size_t)(i*KW + j) * HW);
        const int xc = w0 + j - PADC;
        wgt[i][j][0] = (rowok && xc+0 >= 0 && xc+0 < WD) ? v.x : 0.f;
        wgt[i][j][1] = (rowok && xc+1 >= 0 && xc+1 < WD) ? v.y : 0.f;
        wgt[i][j][2] = (rowok && xc+2 >= 0 && xc+2 < WD) ? v.z : 0.f;
        wgt[i][j][3] = (rowok && xc+3 >= 0 && xc+3 < WD) ? v.w : 0.f;
      }
    }
  }
  #pragma unroll
  for (int i = 0; i < KH; ++i)
    #pragma unroll
    for (int j = 0; j < KW; ++j)
      #pragma unroll
      for (int p = 0; p < 4; ++p)
        asm volatile("" : "+v"(wgt[i][j][p]));   // pin: no remat from memory

  // ---- guard zeroing (NaN-proof: guard reads are zero-weighted but 0*NaN=NaN)
  if (t < GUARD) {
    lds0[t] = 0.f; lds0[GUARD + PATCH_ROWS*ROWF + t] = 0.f;
    lds1[t] = 0.f; lds1[GUARD + PATCH_ROWS*ROWF + t] = 0.f;
  }

  // ---- staging geometry ----
  const int  rrA  = r;
  const int  rrB  = 8 + r;
  const bool hasB = (t < 192);                 // wave-uniform
  const int  hxA  = min(HD-1, max(0, h0 - PADC + rrA));
  const int  hxB  = min(HD-1, max(0, h0 - PADC + rrB));
  const int  srcA = hxA * WD + w0;
  const int  srcB = hxB * WD + w0;
  const int  dstA = GUARD + rrA * ROWF + w0;
  const int  dstB = GUARD + rrB * ROWF + w0;

  const float* xn   = x   + ((size_t)(n * CD + c0)) * HW;
  float*       outp = out + ((size_t)(n * CD + c0)) * HW + h * WD + w0;

  // asm base pointers: &buf[GUARD + r*ROWF + w0 - 4] = &buf[r*128 + 4*l]
  lds_f* P0 = (lds_f*)&lds0[0] + (r * ROWF + (l << 2));
  lds_f* P1 = (lds_f*)&lds1[0] + (r * ROWF + (l << 2));

#define CH_COMPUTE(P)                                                     \
  do {                                                                    \
    f32x4 A0, A1, A2, B0, B1, B2;                                         \
    DS_ISSUE3(P, 0, 16, 32, A0, A1, A2);                                  \
    DS_ISSUE3(P, 512, 528, 544, B0, B1, B2);                              \
    LGKM_WAIT(3, A0, A1, A2); ROW_FMA(0, A0, A1, A2);                     \
    DS_ISSUE3(P, 1024, 1040, 1056, A0, A1, A2);                           \
    LGKM_WAIT(3, B0, B1, B2); ROW_FMA(1, B0, B1, B2);                     \
    DS_ISSUE3(P, 1536, 1552, 1568, B0, B1, B2);                           \
    LGKM_WAIT(3, A0, A1, A2); ROW_FMA(2, A0, A1, A2);                     \
    DS_ISSUE3(P, 2048, 2064, 2080, A0, A1, A2);                           \
    LGKM_WAIT(3, B0, B1, B2); ROW_FMA(3, B0, B1, B2);                     \
    DS_ISSUE3(P, 2560, 2576, 2592, B0, B1, B2);                           \
    LGKM_WAIT(3, A0, A1, A2); ROW_FMA(4, A0, A1, A2);                     \
    DS_ISSUE3(P, 3072, 3088, 3104, A0, A1, A2);                           \
    LGKM_WAIT(3, B0, B1, B2); ROW_FMA(5, B0, B1, B2);                     \
    LGKM_WAIT(0, A0, A1, A2); ROW_FMA(6, A0, A1, A2);                     \
  } while (0)

#define ROW_FMA(I, Q0, Q1, Q2)                                            \
  _Pragma("unroll")                                                       \
  for (int j = 0; j < KW; ++j) {                                          \
    ax += wgt[I][j][0] * xk(Q0, Q1, Q2, j + 1);                           \
    ay += wgt[I][j][1] * xk(Q0, Q1, Q2, j + 2);                           \
    az += wgt[I][j][2] * xk(Q0, Q1, Q2, j + 3);                           \
    aw += wgt[I][j][3] * xk(Q0, Q1, Q2, j + 4);                           \
  }

#define BODY(NXTARR, CURP, CC)                                            \
  do {                                                                    \
    if ((CC) + 1 < CPB) {                                                 \
      const float* xs = xn + ((CC) + 1) * HW;                             \
      gload_lds16(xs + srcA, &NXTARR[dstA]);                              \
      if (hasB) gload_lds16(xs + srcB, &NXTARR[dstB]);                    \
    }                                                                     \
    __builtin_amdgcn_sched_barrier(0);                                    \
    float ax = 0.f, ay = 0.f, az = 0.f, aw = 0.f;                         \
    CH_COMPUTE(CURP);                                                     \
    float4 o; o.x = ax; o.y = ay; o.z = az; o.w = aw;                     \
    *(float4*)(outp + (CC) * HW) = o;                                     \
    asm volatile("s_waitcnt vmcnt(1)" ::: "memory");                      \
    __builtin_amdgcn_s_barrier();                                         \
    __builtin_amdgcn_sched_barrier(0);                                    \
  } while (0)

  // ---- prologue: stage channel 0 into buffer 0 ----
  gload_lds16(xn + srcA, &lds0[dstA]);
  if (hasB) gload_lds16(xn + srcB, &lds0[dstB]);
  asm volatile("s_waitcnt vmcnt(0) lgkmcnt(0)" ::: "memory");
  __builtin_amdgcn_s_barrier();
  __builtin_amdgcn_sched_barrier(0);

  #pragma unroll 1
  for (int cc = 0; cc < CPB; cc += 2) {
    BODY(lds1, P0, cc);        // compute buf0 / stage buf1
    BODY(lds0, P1, cc + 1);    // compute buf1 / stage buf0
  }

#undef CH_COMPUTE
#undef ROW_FMA
#undef BODY
}

extern "C" void kernel_launch(void* const* d_in, const int* in_sizes, int n_in,
                              void* d_out, int out_size, void* d_ws, size_t ws_size,
                              hipStream_t stream) {
  const float* x  = (const float*)d_in[0];
  const float* wt = (const float*)d_in[1];
  float* out      = (float*)d_out;
  hipLaunchKernelGGL(dyconv_kernel, dim3(512), dim3(256), 0, stream, x, wt, out);
}

// Round 4
// 269.641 us; speedup vs baseline: 1.3344x; 1.0844x over previous
//
#include <hip/hip_runtime.h>
#include <stdint.h>

// Per-pixel dynamic (involution) conv, N=8 C=256 H=W=128, K=7x7, pad=3, G=1.
// out[n,c,h,w] = sum_{i,j} weight[n,0,i,j,h,w] * x[n,c,h-3+i,w-3+j]
//
// Round-4 changes vs round-3 (VGPR=128 -> weights were spilled/AGPR-shuttled;
// ~6.6 GB L1/L2 re-read traffic was the residual cost):
//  - __launch_bounds__(256, 1): VGPR cap 512 so the allocator has no reason to
//    spill the 196 pinned weights (grid=512 blocks caps occupancy at 2 blk/CU
//    anyway; ~240 VGPR still gives 2 waves/SIMD)
//  - depth-2 staging: 4 LDS buffers, stage cc+2 at iter cc, steady-state
//    s_waitcnt vmcnt(4) (stage latency gets a full iteration to land)
//  - uniform staging: patch padded to 16 rows, every thread stages exactly
//    2 quads -> vmcnt arithmetic identical across all waves

#define KH 7
#define KW 7
#define PADC 3
#define HD 128
#define WD 128
#define CD 256
#define TH 8
#define CPB 64
#define SROWS 16               // staged rows (14 needed, padded to 16: uniform)
#define ROWF 128               // floats per LDS row (512 B = 32 lanes x 16 B)
#define GUARD 4
#define BUFQ (GUARD + SROWS*ROWF)   // 2052 floats per buffer
#define NBUF 4
#define HW (HD*WD)

typedef float f32x4 __attribute__((ext_vector_type(4)));
typedef __attribute__((address_space(3))) float lds_f;

__device__ __forceinline__ void gload_lds16(const float* g, float* l) {
  __builtin_amdgcn_global_load_lds(
      (const __attribute__((address_space(1))) void*)g,
      (__attribute__((address_space(3))) void*)l, 16, 0, 0);
}

// issue 3 ds_read_b128 at immediate byte offsets (no wait)
#define DS_ISSUE3(P, O0, O1, O2, Q0, Q1, Q2)                        \
  asm volatile("ds_read_b128 %0, %3 offset:" #O0 "\n\t"             \
               "ds_read_b128 %1, %3 offset:" #O1 "\n\t"             \
               "ds_read_b128 %2, %3 offset:" #O2                    \
               : "=&v"(Q0), "=&v"(Q1), "=&v"(Q2) : "v"(P))

// counted wait; ties the waited-on regs so consumers can't hoist above
#define LGKM_WAIT(N, Q0, Q1, Q2)                                    \
  asm volatile("s_waitcnt lgkmcnt(" #N ")" : "+v"(Q0), "+v"(Q1), "+v"(Q2))

__device__ __forceinline__ float xk(const f32x4 a, const f32x4 b,
                                    const f32x4 c, const int k) {
  return k < 4 ? a[k] : (k < 8 ? b[k - 4] : c[k - 8]);
}

__global__ __launch_bounds__(256, 1)
void dyconv_kernel(const float* __restrict__ x,
                   const float* __restrict__ wt,
                   float* __restrict__ out) {
  __shared__ __align__(16) float lds4[NBUF][BUFQ];

  const int t  = threadIdx.x;
  const int l  = t & 31;
  const int r  = t >> 5;
  const int w0 = l << 2;

  const int bid   = blockIdx.x;
  const int chunk = bid & 3;
  const int strip = (bid >> 2) & 15;
  const int n     = bid >> 6;
  const int h0    = strip * TH;
  const int h     = h0 + r;
  const int c0    = chunk * CPB;

  // ---- per-pixel weights: load, zero out-of-image taps, force residency ----
  float wgt[KH][KW][4];
  {
    const float* wb = wt + (size_t)n * (KH*KW) * HW + h * WD + w0;
    #pragma unroll
    for (int i = 0; i < KH; ++i) {
      const int hx = h + i - PADC;
      const bool rowok = (hx >= 0) && (hx < HD);
      #pragma unroll
      for (int j = 0; j < KW; ++j) {
        float4 v = *(const float4*)(wb + (size_t)(i*KW + j) * HW);
        const int xc = w0 + j - PADC;
        wgt[i][j][0] = (rowok && xc+0 >= 0 && xc+0 < WD) ? v.x : 0.f;
        wgt[i][j][1] = (rowok && xc+1 >= 0 && xc+1 < WD) ? v.y : 0.f;
        wgt[i][j][2] = (rowok && xc+2 >= 0 && xc+2 < WD) ? v.z : 0.f;
        wgt[i][j][3] = (rowok && xc+3 >= 0 && xc+3 < WD) ? v.w : 0.f;
      }
    }
  }
  #pragma unroll
  for (int i = 0; i < KH; ++i)
    #pragma unroll
    for (int j = 0; j < KW; ++j)
      #pragma unroll
      for (int p = 0; p < 4; ++p)
        asm volatile("" : "+v"(wgt[i][j][p]));   // pin: no remat from memory

  // ---- zero the 4-float front guard of each buffer (left edge of row 0) ----
  if (t < NBUF * GUARD) lds4[t >> 2][t & 3] = 0.f;

  // ---- staging geometry: every thread stages exactly 2 quads ----
  const int rrA  = r;            // rows 0..7
  const int rrB  = 8 + r;        // rows 8..15 (14,15 = padding, never read)
  const int hxA  = min(HD-1, max(0, h0 - PADC + rrA));
  const int hxB  = min(HD-1, max(0, h0 - PADC + rrB));
  const int srcA = hxA * WD + w0;
  const int srcB = hxB * WD + w0;
  const int dstA = GUARD + rrA * ROWF + w0;
  const int dstB = GUARD + rrB * ROWF + w0;

  const float* xn   = x   + ((size_t)(n * CD + c0)) * HW;
  float*       outp = out + ((size_t)(n * CD + c0)) * HW + h * WD + w0;

  // per-thread LDS read base (buffer 0): &lds4[0][GUARD + r*ROWF + w0 - 4]
  lds_f* Pb = (lds_f*)&lds4[0][0] + (r * ROWF + (l << 2));

#define STAGE2(C)                                                         \
  do {                                                                    \
    const float* xs = xn + (size_t)(C) * HW;                              \
    float* B = &lds4[(C) & 3][0];                                         \
    gload_lds16(xs + srcA, B + dstA);                                     \
    gload_lds16(xs + srcB, B + dstB);                                     \
  } while (0)

#define ROW_FMA(I, Q0, Q1, Q2)                                            \
  _Pragma("unroll")                                                       \
  for (int j = 0; j < KW; ++j) {                                          \
    ax += wgt[I][j][0] * xk(Q0, Q1, Q2, j + 1);                           \
    ay += wgt[I][j][1] * xk(Q0, Q1, Q2, j + 2);                           \
    az += wgt[I][j][2] * xk(Q0, Q1, Q2, j + 3);                           \
    aw += wgt[I][j][3] * xk(Q0, Q1, Q2, j + 4);                           \
  }

#define CH_COMPUTE(P)                                                     \
  do {                                                                    \
    f32x4 A0, A1, A2, B0, B1, B2;                                         \
    DS_ISSUE3(P, 0, 16, 32, A0, A1, A2);                                  \
    DS_ISSUE3(P, 512, 528, 544, B0, B1, B2);                              \
    LGKM_WAIT(3, A0, A1, A2); ROW_FMA(0, A0, A1, A2);                     \
    DS_ISSUE3(P, 1024, 1040, 1056, A0, A1, A2);                           \
    LGKM_WAIT(3, B0, B1, B2); ROW_FMA(1, B0, B1, B2);                     \
    DS_ISSUE3(P, 1536, 1552, 1568, B0, B1, B2);                           \
    LGKM_WAIT(3, A0, A1, A2); ROW_FMA(2, A0, A1, A2);                     \
    DS_ISSUE3(P, 2048, 2064, 2080, A0, A1, A2);                           \
    LGKM_WAIT(3, B0, B1, B2); ROW_FMA(3, B0, B1, B2);                     \
    DS_ISSUE3(P, 2560, 2576, 2592, B0, B1, B2);                           \
    LGKM_WAIT(3, A0, A1, A2); ROW_FMA(4, A0, A1, A2);                     \
    DS_ISSUE3(P, 3072, 3088, 3104, A0, A1, A2);                           \
    LGKM_WAIT(3, B0, B1, B2); ROW_FMA(5, B0, B1, B2);                     \
    LGKM_WAIT(0, A0, A1, A2); ROW_FMA(6, A0, A1, A2);                     \
  } while (0)

#define COMPUTE_STORE(CC)                                                 \
  do {                                                                    \
    lds_f* P = Pb + ((CC) & 3) * BUFQ;                                    \
    float ax = 0.f, ay = 0.f, az = 0.f, aw = 0.f;                         \
    CH_COMPUTE(P);                                                        \
    float4 o; o.x = ax; o.y = ay; o.z = az; o.w = aw;                     \
    *(float4*)(outp + (size_t)(CC) * HW) = o;                             \
  } while (0)

  // ---- prologue: stage channels 0 and 1 into buffers 0 and 1 ----
  STAGE2(0);
  STAGE2(1);
  asm volatile("s_waitcnt vmcnt(0) lgkmcnt(0)" ::: "memory");
  __builtin_amdgcn_s_barrier();
  __builtin_amdgcn_sched_barrier(0);

  // ---- steady state: iter cc stages cc+2, computes cc, waits vmcnt(4) ----
  // in-order vmem queue at end of iter cc (need stage(cc+1) retired):
  //   store(cc-1), stageA(cc+2), stageB(cc+2), store(cc) = 4 newer ops
  #pragma unroll 1
  for (int cc = 0; cc < CPB - 2; ++cc) {
    STAGE2(cc + 2);
    __builtin_amdgcn_sched_barrier(0);
    COMPUTE_STORE(cc);
    asm volatile("s_waitcnt vmcnt(4)" ::: "memory");
    __builtin_amdgcn_s_barrier();
    __builtin_amdgcn_sched_barrier(0);
  }
  // cc = 62: no stage; need stage(63) retired -> newer: store(61), store(62)
  COMPUTE_STORE(CPB - 2);
  asm volatile("s_waitcnt vmcnt(2)" ::: "memory");
  __builtin_amdgcn_s_barrier();
  __builtin_amdgcn_sched_barrier(0);
  // cc = 63: last channel, no wait needed after
  COMPUTE_STORE(CPB - 1);

#undef STAGE2
#undef ROW_FMA
#undef CH_COMPUTE
#undef COMPUTE_STORE
}

extern "C" void kernel_launch(void* const* d_in, const int* in_sizes, int n_in,
                              void* d_out, int out_size, void* d_ws, size_t ws_size,
                              hipStream_t stream) {
  const float* x  = (const float*)d_in[0];
  const float* wt = (const float*)d_in[1];
  float* out      = (float*)d_out;
  hipLaunchKernelGGL(dyconv_kernel, dim3(512), dim3(256), 0, stream, x, wt, out);
}